// Round 1
// baseline (31691.577 us; speedup 1.0000x reference)
//
#include <hip/hip_runtime.h>
#include <hip/hip_bf16.h>
#include <cstddef>

// Problem constants (fixed by the harness shapes)
#define NINP 4096
#define NHID 512
#define G4   2048   // 4*NHID
#define NTOK 50257
#define BSZ  32
#define T_ENC 80
#define T_DEC 40

// ---------------------------------------------------------------------------
// Generic fp32 GEMM:  Z[m][n] = bias[n] + sum_k X[m*ldx+k] * W[n*ldw+k]
// X row-major [M,K] (stride ldx), W row-major [N,K] (stride ldw).
// BM=BN=64, BK=16, 256 threads, 4x4 per thread. M must be multiple of 64.
// ---------------------------------------------------------------------------
__global__ __launch_bounds__(256) void gemm_nt(
    const float* __restrict__ X, int ldx,
    const float* __restrict__ W, int ldw,
    const float* __restrict__ bias,
    float* __restrict__ Z, int ldz,
    int M, int N, int K)
{
    __shared__ float Xs[16][68];
    __shared__ float Ws[16][68];
    const int tid = threadIdx.x;
    const int bm = blockIdx.y * 64;
    const int bn = blockIdx.x * 64;
    const int tx = tid & 15;   // n direction
    const int ty = tid >> 4;   // m direction

    float acc[4][4] = {};

    for (int k0 = 0; k0 < K; k0 += 16) {
        #pragma unroll
        for (int i = 0; i < 4; i++) {
            int e = tid + i * 256;       // 0..1023
            int m = e >> 4;              // 0..63
            int k = e & 15;              // 0..15
            Xs[k][m] = X[(size_t)(bm + m) * ldx + k0 + k];
            int n = m;
            Ws[k][n] = (bn + n < N) ? W[(size_t)(bn + n) * ldw + k0 + k] : 0.f;
        }
        __syncthreads();
        #pragma unroll
        for (int k = 0; k < 16; k++) {
            float xv[4], wv[4];
            #pragma unroll
            for (int i = 0; i < 4; i++) xv[i] = Xs[k][ty * 4 + i];
            #pragma unroll
            for (int j = 0; j < 4; j++) wv[j] = Ws[k][tx * 4 + j];
            #pragma unroll
            for (int i = 0; i < 4; i++)
                #pragma unroll
                for (int j = 0; j < 4; j++)
                    acc[i][j] += xv[i] * wv[j];
        }
        __syncthreads();
    }

    #pragma unroll
    for (int i = 0; i < 4; i++) {
        int m = bm + ty * 4 + i;
        #pragma unroll
        for (int j = 0; j < 4; j++) {
            int n = bn + tx * 4 + j;
            if (n < N)
                Z[(size_t)m * ldz + n] = acc[i][j] + (bias ? bias[n] : 0.f);
        }
    }
}

// ---------------------------------------------------------------------------
// One LSTM recurrence step.
// z = (Zx ? Zx : 0) + h @ Whh^T + bias ; gates i,f,g,o ; update c,h.
// Grid: 64 blocks x 256 threads. Block b handles 8 h-columns x 32 batches.
// ---------------------------------------------------------------------------
__global__ __launch_bounds__(256) void lstm_step_kernel(
    const float* __restrict__ Zx,    // [B, 2048] or nullptr
    const float* __restrict__ bias,  // [2048]
    const float* __restrict__ Whh,   // [2048, 512]
    float* __restrict__ h,           // [B, 512]  (in/out)
    float* __restrict__ c,           // [B, 512]  (in/out)
    float* __restrict__ out_h)       // [B, 512] slice for this t, or nullptr
{
    __shared__ float hs[BSZ][NHID + 4];   // pad 4 floats -> row stride 516
    const int tid = threadIdx.x;

    // stage h into LDS (16384 floats / 256 threads)
    for (int i = tid; i < BSZ * NHID; i += 256) {
        int b = i >> 9, k = i & 511;
        hs[b][k] = h[i];
    }
    __syncthreads();

    const int jc = blockIdx.x * 8 + (tid & 7);   // 0..511
    const int b  = tid >> 3;                     // 0..31
    const float* hrow = hs[b];
    const float* wi = Whh + (size_t)jc * NHID;
    const float* wf = Whh + (size_t)(512 + jc) * NHID;
    const float* wg = Whh + (size_t)(1024 + jc) * NHID;
    const float* wo = Whh + (size_t)(1536 + jc) * NHID;

    float zi = 0.f, zf = 0.f, zg = 0.f, zo = 0.f;
    #pragma unroll 4
    for (int k = 0; k < NHID; k += 4) {
        float4 hv = *(const float4*)&hrow[k];
        float4 a  = *(const float4*)&wi[k];
        float4 f4 = *(const float4*)&wf[k];
        float4 g4 = *(const float4*)&wg[k];
        float4 o4 = *(const float4*)&wo[k];
        zi += hv.x * a.x  + hv.y * a.y  + hv.z * a.z  + hv.w * a.w;
        zf += hv.x * f4.x + hv.y * f4.y + hv.z * f4.z + hv.w * f4.w;
        zg += hv.x * g4.x + hv.y * g4.y + hv.z * g4.z + hv.w * g4.w;
        zo += hv.x * o4.x + hv.y * o4.y + hv.z * o4.z + hv.w * o4.w;
    }

    if (Zx) {
        const float* zrow = Zx + (size_t)b * G4;
        zi += zrow[jc];
        zf += zrow[512 + jc];
        zg += zrow[1024 + jc];
        zo += zrow[1536 + jc];
    }
    zi += bias[jc];
    zf += bias[512 + jc];
    zg += bias[1024 + jc];
    zo += bias[1536 + jc];

    float ig = 1.f / (1.f + __expf(-zi));
    float fg = 1.f / (1.f + __expf(-zf));
    float gg = tanhf(zg);
    float og = 1.f / (1.f + __expf(-zo));

    int idx = b * NHID + jc;
    float cn = fg * c[idx] + ig * gg;
    float hn = og * tanhf(cn);
    c[idx] = cn;
    h[idx] = hn;
    if (out_h) out_h[idx] = hn;
}

// ---------------------------------------------------------------------------
// bias2[j] = l2_b0[j] + sum_h (W_emb[h*NTOK + 0] + b_emb[h]) * Wih0[j*1024 + h]
// (constant BOS-embedding contribution of decoder lstm2 layer0)
// ---------------------------------------------------------------------------
__global__ __launch_bounds__(256) void bias2_kernel(
    const float* __restrict__ W_emb,  // [512, NTOK]
    const float* __restrict__ b_emb,  // [512]
    const float* __restrict__ Wih0,   // [2048, 1024]
    const float* __restrict__ b0,     // [2048]
    float* __restrict__ bias2)        // [2048]
{
    __shared__ float bos[NHID];
    const int tid = threadIdx.x;
    for (int i = tid; i < NHID; i += 256)
        bos[i] = W_emb[(size_t)i * NTOK] + b_emb[i];
    __syncthreads();
    int j = blockIdx.x * 256 + tid;   // 8 blocks -> 2048
    float acc = b0[j];
    for (int k = 0; k < NHID; k++)
        acc += bos[k] * Wih0[(size_t)j * 1024 + k];
    bias2[j] = acc;
}

// ---------------------------------------------------------------------------
// In-place log_softmax over rows of 50257. One block per row.
// ---------------------------------------------------------------------------
__global__ __launch_bounds__(256) void logsoftmax_kernel(float* __restrict__ logits)
{
    const size_t row = blockIdx.x;
    float* p = logits + row * (size_t)NTOK;
    const int tid = threadIdx.x;

    float m = -1e30f;
    for (int i = tid; i < NTOK; i += 256) m = fmaxf(m, p[i]);
    #pragma unroll
    for (int off = 32; off > 0; off >>= 1) m = fmaxf(m, __shfl_down(m, off));
    __shared__ float sm[4];
    if ((tid & 63) == 0) sm[tid >> 6] = m;
    __syncthreads();
    m = fmaxf(fmaxf(sm[0], sm[1]), fmaxf(sm[2], sm[3]));

    float s = 0.f;
    for (int i = tid; i < NTOK; i += 256) s += __expf(p[i] - m);
    #pragma unroll
    for (int off = 32; off > 0; off >>= 1) s += __shfl_down(s, off);
    __shared__ float ss[4];
    if ((tid & 63) == 0) ss[tid >> 6] = s;
    __syncthreads();
    s = ss[0] + ss[1] + ss[2] + ss[3];

    float lse = m + logf(s);
    for (int i = tid; i < NTOK; i += 256) p[i] = p[i] - lse;
}

// ---------------------------------------------------------------------------
extern "C" void kernel_launch(void* const* d_in, const int* in_sizes, int n_in,
                              void* d_out, int out_size, void* d_ws, size_t ws_size,
                              hipStream_t stream)
{
    const float* inp     = (const float*)d_in[0];   // [80,32,4096]
    const float* hid1_h  = (const float*)d_in[1];   // [2,32,512]
    const float* hid1_c  = (const float*)d_in[2];
    const float* hid2_h  = (const float*)d_in[3];
    const float* hid2_c  = (const float*)d_in[4];
    const float* l1_Wih0 = (const float*)d_in[5];   // [2048,4096]
    const float* l1_Whh0 = (const float*)d_in[6];   // [2048,512]
    const float* l1_b0   = (const float*)d_in[7];   // [2048]
    const float* l1_Wih1 = (const float*)d_in[8];   // [2048,512]
    const float* l1_Whh1 = (const float*)d_in[9];
    const float* l1_b1   = (const float*)d_in[10];
    const float* l2_Wih0 = (const float*)d_in[11];  // [2048,1024]
    const float* l2_Whh0 = (const float*)d_in[12];
    const float* l2_b0   = (const float*)d_in[13];
    const float* l2_Wih1 = (const float*)d_in[14];
    const float* l2_Whh1 = (const float*)d_in[15];
    const float* l2_b1   = (const float*)d_in[16];
    const float* W_out   = (const float*)d_in[17];  // [50257,512]
    const float* b_out   = (const float*)d_in[18];  // [50257]
    const float* W_emb   = (const float*)d_in[19];  // [512,50257]
    const float* b_emb   = (const float*)d_in[20];  // [512]
    // d_in[21] = target_len (=40, fixed by out_size) — compile-time constant here.

    float* out = (float*)d_out;   // [40,32,50257]
    float* ws  = (float*)d_ws;

    // workspace layout (floats)
    float* Zx    = ws;                       // [2560, 2048]   5,242,880
    float* enc0  = ws + 5242880;             // [2560, 512]    1,310,720  (reused as dec0)
    float* enc1  = ws + 6553600;             // [2560, 512]               (reused as dec1)
    float* enc2  = ws + 7864320;             // [2560, 512]               (reused as dec2_0)
    float* dec3  = ws + 9175040;             // [1280, 512]      655,360
    float* H1    = ws + 9830400;             // [2,32,512]        32,768
    float* C1    = H1 + 32768;
    float* H2    = C1 + 32768;
    float* C2    = H2 + 32768;
    float* bias2 = C2 + 32768;               // [2048]

    // init recurrent states from inputs (each [2,32,512] = 131072 bytes)
    hipMemcpyAsync(H1, hid1_h, 131072, hipMemcpyDeviceToDevice, stream);
    hipMemcpyAsync(C1, hid1_c, 131072, hipMemcpyDeviceToDevice, stream);
    hipMemcpyAsync(H2, hid2_h, 131072, hipMemcpyDeviceToDevice, stream);
    hipMemcpyAsync(C2, hid2_c, 131072, hipMemcpyDeviceToDevice, stream);

    auto gemm = [&](const float* X, int ldx, const float* W, int ldw,
                    const float* bias, float* Z, int ldz, int M, int N, int K) {
        dim3 grid((N + 63) / 64, M / 64);
        gemm_nt<<<grid, dim3(256), 0, stream>>>(X, ldx, W, ldw, bias, Z, ldz, M, N, K);
    };
    auto scan = [&](int T, const float* Zx_, const float* bias_, const float* Whh_,
                    float* h_, float* c_, float* outp) {
        for (int t = 0; t < T; t++)
            lstm_step_kernel<<<64, 256, 0, stream>>>(
                Zx_ ? Zx_ + (size_t)t * BSZ * G4 : nullptr,
                bias_, Whh_, h_, c_,
                outp ? outp + (size_t)t * BSZ * NHID : nullptr);
    };

    // ---- encoder lstm1 ----
    gemm(inp, NINP, l1_Wih0, NINP, nullptr, Zx, G4, T_ENC * BSZ, G4, NINP);
    scan(T_ENC, Zx, l1_b0, l1_Whh0, H1, C1, enc0);
    gemm(enc0, NHID, l1_Wih1, NHID, nullptr, Zx, G4, T_ENC * BSZ, G4, NHID);
    scan(T_ENC, Zx, l1_b1, l1_Whh1, H1 + 16384, C1 + 16384, enc1);

    // ---- encoder lstm2 (input = [zeros | enc1]) ----
    gemm(enc1, NHID, l2_Wih0 + 512, 2 * NHID, nullptr, Zx, G4, T_ENC * BSZ, G4, NHID);
    scan(T_ENC, Zx, l2_b0, l2_Whh0, H2, C2, enc2);
    gemm(enc2, NHID, l2_Wih1, NHID, nullptr, Zx, G4, T_ENC * BSZ, G4, NHID);
    scan(T_ENC, Zx, l2_b1, l2_Whh1, H2 + 16384, C2 + 16384, nullptr);

    // ---- decoder lstm1 (input = zeros -> no input GEMM for layer 0) ----
    scan(T_DEC, nullptr, l1_b0, l1_Whh0, H1, C1, enc0 /* dec0 */);
    gemm(enc0, NHID, l1_Wih1, NHID, nullptr, Zx, G4, T_DEC * BSZ, G4, NHID);
    scan(T_DEC, Zx, l1_b1, l1_Whh1, H1 + 16384, C1 + 16384, enc1 /* dec1 */);

    // ---- decoder lstm2 (input = [const BOS emb | dec1]) ----
    bias2_kernel<<<8, 256, 0, stream>>>(W_emb, b_emb, l2_Wih0, l2_b0, bias2);
    gemm(enc1, NHID, l2_Wih0 + 512, 2 * NHID, nullptr, Zx, G4, T_DEC * BSZ, G4, NHID);
    scan(T_DEC, Zx, bias2, l2_Whh0, H2, C2, enc2 /* dec2_0 */);
    gemm(enc2, NHID, l2_Wih1, NHID, nullptr, Zx, G4, T_DEC * BSZ, G4, NHID);
    scan(T_DEC, Zx, l2_b1, l2_Whh1, H2 + 16384, C2 + 16384, dec3);

    // ---- vocab projection + log_softmax ----
    gemm(dec3, NHID, W_out, NHID, b_out, out, NTOK, T_DEC * BSZ, NTOK, NHID);
    logsoftmax_kernel<<<1280, dim3(256), 0, stream>>>(out);
}

// Round 2
// 29645.541 us; speedup vs baseline: 1.0690x; 1.0690x over previous
//
#include <hip/hip_runtime.h>
#include <hip/hip_bf16.h>
#include <cstddef>

// Problem constants (fixed by the harness shapes)
#define NINP 4096
#define NHID 512
#define G4   2048   // 4*NHID
#define NTOK 50257
#define BSZ  32
#define T_ENC 80
#define T_DEC 40

typedef __attribute__((ext_vector_type(4))) float  f32x4;
typedef __attribute__((ext_vector_type(4))) __bf16 bf16x4;
typedef __attribute__((ext_vector_type(8))) __bf16 bf16x8;

// ---------------------------------------------------------------------------
// XOR-swizzled byte offset inside one 16 KB LDS tile of [128 rows][64 k] bf16.
// Row stride 128 B; 16B-slot index (k>>3) is XORed with (row&7) so that the
// 16 lanes of a fragment read (rows r..r+15, same k) hit distinct banks.
// ---------------------------------------------------------------------------
__device__ __forceinline__ int sw_off(int r, int k) {
    return r * 128 + ((((k >> 3) ^ (r & 7)) << 4) | ((k & 7) << 1));
}

__device__ __forceinline__ void split4(const float4& v, bf16x4& h, bf16x4& l) {
    float a0 = v.x, a1 = v.y, a2 = v.z, a3 = v.w;
    __bf16 h0 = (__bf16)a0, h1 = (__bf16)a1, h2 = (__bf16)a2, h3 = (__bf16)a3;
    h[0] = h0; h[1] = h1; h[2] = h2; h[3] = h3;
    l[0] = (__bf16)(a0 - (float)h0);
    l[1] = (__bf16)(a1 - (float)h1);
    l[2] = (__bf16)(a2 - (float)h2);
    l[3] = (__bf16)(a3 - (float)h3);
}

// ---------------------------------------------------------------------------
// Compensated bf16 MFMA GEMM:  Z[m][n] = bias[n] + sum_k A[m][k] * B[n][k]
// A fp32 [M,K] (lda), B fp32 [N,K] (ldb). In-kernel hi/lo split:
//   A*B ~= Ah*Bh + Al*Bh + Ah*Bl   (error ~2^-18 relative, fp32-grade)
// 128x128 tile, BK=64, 256 threads (4 waves, each a 64x64 quadrant of 4x4
// 16x16x32 MFMA fragments). LDS: 4 swizzled tiles (Ah,Al,Bh,Bl) = 64 KB.
// M must be a multiple of 128; K a multiple of 64; N arbitrary (guarded).
// ---------------------------------------------------------------------------
__global__ __launch_bounds__(256) void gemm_hilo(
    const float* __restrict__ A, int lda,
    const float* __restrict__ B, int ldb,
    const float* __restrict__ bias,
    float* __restrict__ Z, int ldz,
    int N, int K)
{
    __shared__ __align__(16) char lds[65536];
    const int tid  = threadIdx.x;
    const int bm   = blockIdx.y * 128;
    const int bn   = blockIdx.x * 128;
    const int wave = tid >> 6;
    const int lane = tid & 63;
    const int wm   = (wave >> 1) * 64;   // wave row quadrant
    const int wn   = (wave & 1) * 64;    // wave col quadrant
    const int lr   = lane & 15;
    const int kg   = lane >> 4;          // 0..3

    // staging decomposition: thread covers rows (i*16 + tid>>4), k = (tid&15)*4
    const int rr = tid >> 4;
    const int kk = (tid & 15) * 4;

    f32x4 acc[4][4] = {};

    for (int k0 = 0; k0 < K; k0 += 64) {
        // ---- load fp32 tiles to registers (no LDS hazard yet) ----
        float4 av[8], bv[8];
        #pragma unroll
        for (int i = 0; i < 8; i++) {
            int r = i * 16 + rr;
            av[i] = *(const float4*)&A[(size_t)(bm + r) * lda + k0 + kk];
            int rb = bn + r;
            if (rb < N)
                bv[i] = *(const float4*)&B[(size_t)rb * ldb + k0 + kk];
            else
                bv[i] = make_float4(0.f, 0.f, 0.f, 0.f);
        }
        __syncthreads();   // previous iteration's reads done before overwrite
        // ---- split to hi/lo and write swizzled LDS tiles ----
        #pragma unroll
        for (int i = 0; i < 8; i++) {
            int r = i * 16 + rr;
            int off = sw_off(r, kk);
            bf16x4 h, l;
            split4(av[i], h, l);
            *(bf16x4*)(lds + off)         = h;
            *(bf16x4*)(lds + 16384 + off) = l;
            split4(bv[i], h, l);
            *(bf16x4*)(lds + 32768 + off) = h;
            *(bf16x4*)(lds + 49152 + off) = l;
        }
        __syncthreads();
        // ---- MFMA: 3 compensation passes over 2 k-slices ----
        #pragma unroll
        for (int ks = 0; ks < 2; ks++) {
            bf16x8 ah[4], al[4], bh[4], bl[4];
            const int kbase = ks * 32 + kg * 8;
            #pragma unroll
            for (int f = 0; f < 4; f++) {
                int offA = sw_off(wm + f * 16 + lr, kbase);
                ah[f] = *(const bf16x8*)(lds + offA);
                al[f] = *(const bf16x8*)(lds + 16384 + offA);
                int offB = sw_off(wn + f * 16 + lr, kbase);
                bh[f] = *(const bf16x8*)(lds + 32768 + offB);
                bl[f] = *(const bf16x8*)(lds + 49152 + offB);
            }
            #pragma unroll
            for (int fm = 0; fm < 4; fm++)
                #pragma unroll
                for (int fn = 0; fn < 4; fn++)
                    acc[fm][fn] = __builtin_amdgcn_mfma_f32_16x16x32_bf16(
                        ah[fm], bh[fn], acc[fm][fn], 0, 0, 0);
            #pragma unroll
            for (int fm = 0; fm < 4; fm++)
                #pragma unroll
                for (int fn = 0; fn < 4; fn++) {
                    acc[fm][fn] = __builtin_amdgcn_mfma_f32_16x16x32_bf16(
                        al[fm], bh[fn], acc[fm][fn], 0, 0, 0);
                    acc[fm][fn] = __builtin_amdgcn_mfma_f32_16x16x32_bf16(
                        ah[fm], bl[fn], acc[fm][fn], 0, 0, 0);
                }
        }
    }

    // ---- epilogue: C/D layout col=lane&15, row=(lane>>4)*4+j ----
    #pragma unroll
    for (int fn = 0; fn < 4; fn++) {
        int col = bn + wn + fn * 16 + lr;
        if (col < N) {
            float bb = bias ? bias[col] : 0.f;
            #pragma unroll
            for (int fm = 0; fm < 4; fm++) {
                #pragma unroll
                for (int j = 0; j < 4; j++) {
                    int row = bm + wm + fm * 16 + kg * 4 + j;
                    Z[(size_t)row * ldz + col] = acc[fm][fn][j] + bb;
                }
            }
        }
    }
}

// ---------------------------------------------------------------------------
__device__ __forceinline__ float fast_sigmoid(float x) {
    return 1.f / (1.f + __expf(-x));
}
__device__ __forceinline__ float fast_tanh(float x) {
    // 1 - 2/(e^{2x}+1); saturates correctly at +-inf
    return 1.f - 2.f / (__expf(2.f * x) + 1.f);
}

// ---------------------------------------------------------------------------
// One LSTM recurrence step.
// z = (Zx ? Zx : 0) + h @ Whh^T + bias ; gates i,f,g,o ; update c,h.
// Grid: 64 blocks x 256 threads. Block b handles 8 h-columns x 32 batches.
// ---------------------------------------------------------------------------
__global__ __launch_bounds__(256) void lstm_step_kernel(
    const float* __restrict__ Zx,    // [B, 2048] or nullptr
    const float* __restrict__ bias,  // [2048]
    const float* __restrict__ Whh,   // [2048, 512]
    float* __restrict__ h,           // [B, 512]  (in/out)
    float* __restrict__ c,           // [B, 512]  (in/out)
    float* __restrict__ out_h)       // [B, 512] slice for this t, or nullptr
{
    __shared__ float hs[BSZ][NHID + 4];
    const int tid = threadIdx.x;

    for (int i = tid; i < BSZ * NHID; i += 256) {
        int b = i >> 9, k = i & 511;
        hs[b][k] = h[i];
    }
    __syncthreads();

    const int jc = blockIdx.x * 8 + (tid & 7);
    const int b  = tid >> 3;
    const float* hrow = hs[b];
    const float* wi = Whh + (size_t)jc * NHID;
    const float* wf = Whh + (size_t)(512 + jc) * NHID;
    const float* wg = Whh + (size_t)(1024 + jc) * NHID;
    const float* wo = Whh + (size_t)(1536 + jc) * NHID;

    float zi = 0.f, zf = 0.f, zg = 0.f, zo = 0.f;
    #pragma unroll 4
    for (int k = 0; k < NHID; k += 4) {
        float4 hv = *(const float4*)&hrow[k];
        float4 a  = *(const float4*)&wi[k];
        float4 f4 = *(const float4*)&wf[k];
        float4 g4 = *(const float4*)&wg[k];
        float4 o4 = *(const float4*)&wo[k];
        zi += hv.x * a.x  + hv.y * a.y  + hv.z * a.z  + hv.w * a.w;
        zf += hv.x * f4.x + hv.y * f4.y + hv.z * f4.z + hv.w * f4.w;
        zg += hv.x * g4.x + hv.y * g4.y + hv.z * g4.z + hv.w * g4.w;
        zo += hv.x * o4.x + hv.y * o4.y + hv.z * o4.z + hv.w * o4.w;
    }

    if (Zx) {
        const float* zrow = Zx + (size_t)b * G4;
        zi += zrow[jc];
        zf += zrow[512 + jc];
        zg += zrow[1024 + jc];
        zo += zrow[1536 + jc];
    }
    zi += bias[jc];
    zf += bias[512 + jc];
    zg += bias[1024 + jc];
    zo += bias[1536 + jc];

    float ig = fast_sigmoid(zi);
    float fg = fast_sigmoid(zf);
    float gg = fast_tanh(zg);
    float og = fast_sigmoid(zo);

    int idx = b * NHID + jc;
    float cn = fg * c[idx] + ig * gg;
    float hn = og * fast_tanh(cn);
    c[idx] = cn;
    h[idx] = hn;
    if (out_h) out_h[idx] = hn;
}

// ---------------------------------------------------------------------------
// bias2[j] = l2_b0[j] + sum_h (W_emb[h*NTOK + 0] + b_emb[h]) * Wih0[j*1024 + h]
// ---------------------------------------------------------------------------
__global__ __launch_bounds__(256) void bias2_kernel(
    const float* __restrict__ W_emb,
    const float* __restrict__ b_emb,
    const float* __restrict__ Wih0,
    const float* __restrict__ b0,
    float* __restrict__ bias2)
{
    __shared__ float bos[NHID];
    const int tid = threadIdx.x;
    for (int i = tid; i < NHID; i += 256)
        bos[i] = W_emb[(size_t)i * NTOK] + b_emb[i];
    __syncthreads();
    int j = blockIdx.x * 256 + tid;
    float acc = b0[j];
    for (int k = 0; k < NHID; k++)
        acc += bos[k] * Wih0[(size_t)j * 1024 + k];
    bias2[j] = acc;
}

// ---------------------------------------------------------------------------
// In-place log_softmax over rows of 50257. One block per row, online max+sum
// (2 read passes + 1 write pass instead of 3+1).
// ---------------------------------------------------------------------------
__global__ __launch_bounds__(256) void logsoftmax_kernel(float* __restrict__ logits)
{
    const size_t row = blockIdx.x;
    float* p = logits + row * (size_t)NTOK;
    const int tid = threadIdx.x;

    float m = -1e30f, s = 0.f;
    for (int i = tid; i < NTOK; i += 256) {
        float x = p[i];
        float mn = fmaxf(m, x);
        s = s * __expf(m - mn) + __expf(x - mn);
        m = mn;
    }
    #pragma unroll
    for (int off = 32; off > 0; off >>= 1) {
        float mo = __shfl_down(m, off);
        float so = __shfl_down(s, off);
        float mn = fmaxf(m, mo);
        s = s * __expf(m - mn) + so * __expf(mo - mn);
        m = mn;
    }
    __shared__ float sm[4], ss[4];
    if ((tid & 63) == 0) { sm[tid >> 6] = m; ss[tid >> 6] = s; }
    __syncthreads();
    float M4 = fmaxf(fmaxf(sm[0], sm[1]), fmaxf(sm[2], sm[3]));
    float S  = ss[0] * __expf(sm[0] - M4) + ss[1] * __expf(sm[1] - M4)
             + ss[2] * __expf(sm[2] - M4) + ss[3] * __expf(sm[3] - M4);
    float lse = M4 + logf(S);
    for (int i = tid; i < NTOK; i += 256) p[i] = p[i] - lse;
}

// ---------------------------------------------------------------------------
extern "C" void kernel_launch(void* const* d_in, const int* in_sizes, int n_in,
                              void* d_out, int out_size, void* d_ws, size_t ws_size,
                              hipStream_t stream)
{
    const float* inp     = (const float*)d_in[0];   // [80,32,4096]
    const float* hid1_h  = (const float*)d_in[1];
    const float* hid1_c  = (const float*)d_in[2];
    const float* hid2_h  = (const float*)d_in[3];
    const float* hid2_c  = (const float*)d_in[4];
    const float* l1_Wih0 = (const float*)d_in[5];   // [2048,4096]
    const float* l1_Whh0 = (const float*)d_in[6];
    const float* l1_b0   = (const float*)d_in[7];
    const float* l1_Wih1 = (const float*)d_in[8];
    const float* l1_Whh1 = (const float*)d_in[9];
    const float* l1_b1   = (const float*)d_in[10];
    const float* l2_Wih0 = (const float*)d_in[11];  // [2048,1024]
    const float* l2_Whh0 = (const float*)d_in[12];
    const float* l2_b0   = (const float*)d_in[13];
    const float* l2_Wih1 = (const float*)d_in[14];
    const float* l2_Whh1 = (const float*)d_in[15];
    const float* l2_b1   = (const float*)d_in[16];
    const float* W_out   = (const float*)d_in[17];  // [50257,512]
    const float* b_out   = (const float*)d_in[18];
    const float* W_emb   = (const float*)d_in[19];  // [512,50257]
    const float* b_emb   = (const float*)d_in[20];

    float* out = (float*)d_out;   // [40,32,50257]
    float* ws  = (float*)d_ws;

    // workspace layout (floats) — identical footprint to round 1 (~40 MB)
    float* Zx    = ws;                       // [2560, 2048]
    float* enc0  = ws + 5242880;             // [2560, 512] (reused as dec0)
    float* enc1  = ws + 6553600;             // [2560, 512] (reused as dec1)
    float* enc2  = ws + 7864320;             // [2560, 512] (reused as dec2_0)
    float* dec3  = ws + 9175040;             // [1280, 512]
    float* H1    = ws + 9830400;             // [2,32,512]
    float* C1    = H1 + 32768;
    float* H2    = C1 + 32768;
    float* C2    = H2 + 32768;
    float* bias2 = C2 + 32768;               // [2048]

    hipMemcpyAsync(H1, hid1_h, 131072, hipMemcpyDeviceToDevice, stream);
    hipMemcpyAsync(C1, hid1_c, 131072, hipMemcpyDeviceToDevice, stream);
    hipMemcpyAsync(H2, hid2_h, 131072, hipMemcpyDeviceToDevice, stream);
    hipMemcpyAsync(C2, hid2_c, 131072, hipMemcpyDeviceToDevice, stream);

    auto gemm = [&](const float* X, int lda, const float* W, int ldw,
                    const float* bias, float* Z, int ldz, int M, int N, int K) {
        dim3 grid((N + 127) / 128, M / 128);
        gemm_hilo<<<grid, dim3(256), 0, stream>>>(X, lda, W, ldw, bias, Z, ldz, N, K);
    };
    auto scan = [&](int T, const float* Zx_, const float* bias_, const float* Whh_,
                    float* h_, float* c_, float* outp) {
        for (int t = 0; t < T; t++)
            lstm_step_kernel<<<64, 256, 0, stream>>>(
                Zx_ ? Zx_ + (size_t)t * BSZ * G4 : nullptr,
                bias_, Whh_, h_, c_,
                outp ? outp + (size_t)t * BSZ * NHID : nullptr);
    };

    // ---- encoder lstm1 ----
    gemm(inp, NINP, l1_Wih0, NINP, nullptr, Zx, G4, T_ENC * BSZ, G4, NINP);
    scan(T_ENC, Zx, l1_b0, l1_Whh0, H1, C1, enc0);
    gemm(enc0, NHID, l1_Wih1, NHID, nullptr, Zx, G4, T_ENC * BSZ, G4, NHID);
    scan(T_ENC, Zx, l1_b1, l1_Whh1, H1 + 16384, C1 + 16384, enc1);

    // ---- encoder lstm2 (input = [zeros | enc1]) ----
    gemm(enc1, NHID, l2_Wih0 + 512, 2 * NHID, nullptr, Zx, G4, T_ENC * BSZ, G4, NHID);
    scan(T_ENC, Zx, l2_b0, l2_Whh0, H2, C2, enc2);
    gemm(enc2, NHID, l2_Wih1, NHID, nullptr, Zx, G4, T_ENC * BSZ, G4, NHID);
    scan(T_ENC, Zx, l2_b1, l2_Whh1, H2 + 16384, C2 + 16384, nullptr);

    // ---- decoder lstm1 (input = zeros -> bias only for layer 0) ----
    scan(T_DEC, nullptr, l1_b0, l1_Whh0, H1, C1, enc0 /* dec0 */);
    gemm(enc0, NHID, l1_Wih1, NHID, nullptr, Zx, G4, T_DEC * BSZ, G4, NHID);
    scan(T_DEC, Zx, l1_b1, l1_Whh1, H1 + 16384, C1 + 16384, enc1 /* dec1 */);

    // ---- decoder lstm2 (input = [const BOS emb | dec1]) ----
    bias2_kernel<<<8, 256, 0, stream>>>(W_emb, b_emb, l2_Wih0, l2_b0, bias2);
    gemm(enc1, NHID, l2_Wih0 + 512, 2 * NHID, nullptr, Zx, G4, T_DEC * BSZ, G4, NHID);
    scan(T_DEC, Zx, bias2, l2_Whh0, H2, C2, enc2 /* dec2_0 */);
    gemm(enc2, NHID, l2_Wih1, NHID, nullptr, Zx, G4, T_DEC * BSZ, G4, NHID);
    scan(T_DEC, Zx, l2_b1, l2_Whh1, H2 + 16384, C2 + 16384, dec3);

    // ---- vocab projection + log_softmax ----
    gemm(dec3, NHID, W_out, NHID, b_out, out, NTOK, T_DEC * BSZ, NTOK, NHID);
    logsoftmax_kernel<<<1280, dim3(256), 0, stream>>>(out);
}

// Round 4
// 7372.233 us; speedup vs baseline: 4.2988x; 4.0212x over previous
//
#include <hip/hip_runtime.h>
#include <hip/hip_bf16.h>
#include <cstddef>

// Problem constants (fixed by the harness shapes)
#define NINP 4096
#define NHID 512
#define G4   2048   // 4*NHID
#define NTOK 50257
#define BSZ  32
#define T_ENC 80
#define T_DEC 40
#define NB   64     // blocks in the persistent scan kernel

typedef __attribute__((ext_vector_type(4))) float  f32x4;
typedef __attribute__((ext_vector_type(4))) __bf16 bf16x4;
typedef __attribute__((ext_vector_type(8))) __bf16 bf16x8;

// ---------------------------------------------------------------------------
// XOR-swizzled byte offset inside an LDS tile of [rows][64 k] bf16 (stride 128B)
// ---------------------------------------------------------------------------
__device__ __forceinline__ int sw_off(int r, int k) {
    return r * 128 + ((((k >> 3) ^ (r & 7)) << 4) | ((k & 7) << 1));
}
// same idea for [rows][512 k] bf16 tiles (stride 1024B) used by the scan kernel
__device__ __forceinline__ int sw512(int r, int k) {
    return r * 1024 + ((((k >> 3) ^ (r & 7)) << 4) | ((k & 7) << 1));
}

__device__ __forceinline__ void split4(const float4& v, bf16x4& h, bf16x4& l) {
    float a0 = v.x, a1 = v.y, a2 = v.z, a3 = v.w;
    __bf16 h0 = (__bf16)a0, h1 = (__bf16)a1, h2 = (__bf16)a2, h3 = (__bf16)a3;
    h[0] = h0; h[1] = h1; h[2] = h2; h[3] = h3;
    l[0] = (__bf16)(a0 - (float)h0);
    l[1] = (__bf16)(a1 - (float)h1);
    l[2] = (__bf16)(a2 - (float)h2);
    l[3] = (__bf16)(a3 - (float)h3);
}

__device__ __forceinline__ unsigned pack_hilo(float x) {
    __bf16 hb = (__bf16)x;
    float hf = (float)hb;
    __bf16 lb = (__bf16)(x - hf);
    union { __bf16 b; unsigned short s; } ch, cl;
    ch.b = hb; cl.b = lb;
    return (unsigned)ch.s | ((unsigned)cl.s << 16);
}

__device__ __forceinline__ float fast_sigmoid(float x) {
    return 1.f / (1.f + __expf(-x));
}
__device__ __forceinline__ float fast_tanh(float x) {
    return 1.f - 2.f / (__expf(2.f * x) + 1.f);
}

// ---------------------------------------------------------------------------
// Compensated bf16 MFMA GEMM:  Z[m][n] = bias[n] + sum_k A[m][k] * B[n][k]
// (unchanged from round 2 — verified correct)
// ---------------------------------------------------------------------------
__global__ __launch_bounds__(256) void gemm_hilo(
    const float* __restrict__ A, int lda,
    const float* __restrict__ B, int ldb,
    const float* __restrict__ bias,
    float* __restrict__ Z, int ldz,
    int N, int K)
{
    __shared__ __align__(16) char lds[65536];
    const int tid  = threadIdx.x;
    const int bm   = blockIdx.y * 128;
    const int bn   = blockIdx.x * 128;
    const int wave = tid >> 6;
    const int lane = tid & 63;
    const int wm   = (wave >> 1) * 64;
    const int wn   = (wave & 1) * 64;
    const int lr   = lane & 15;
    const int kg   = lane >> 4;

    const int rr = tid >> 4;
    const int kk = (tid & 15) * 4;

    f32x4 acc[4][4] = {};

    for (int k0 = 0; k0 < K; k0 += 64) {
        float4 av[8], bv[8];
        #pragma unroll
        for (int i = 0; i < 8; i++) {
            int r = i * 16 + rr;
            av[i] = *(const float4*)&A[(size_t)(bm + r) * lda + k0 + kk];
            int rb = bn + r;
            if (rb < N)
                bv[i] = *(const float4*)&B[(size_t)rb * ldb + k0 + kk];
            else
                bv[i] = make_float4(0.f, 0.f, 0.f, 0.f);
        }
        __syncthreads();
        #pragma unroll
        for (int i = 0; i < 8; i++) {
            int r = i * 16 + rr;
            int off = sw_off(r, kk);
            bf16x4 h, l;
            split4(av[i], h, l);
            *(bf16x4*)(lds + off)         = h;
            *(bf16x4*)(lds + 16384 + off) = l;
            split4(bv[i], h, l);
            *(bf16x4*)(lds + 32768 + off) = h;
            *(bf16x4*)(lds + 49152 + off) = l;
        }
        __syncthreads();
        #pragma unroll
        for (int ks = 0; ks < 2; ks++) {
            bf16x8 ah[4], al[4], bh[4], bl[4];
            const int kbase = ks * 32 + kg * 8;
            #pragma unroll
            for (int f = 0; f < 4; f++) {
                int offA = sw_off(wm + f * 16 + lr, kbase);
                ah[f] = *(const bf16x8*)(lds + offA);
                al[f] = *(const bf16x8*)(lds + 16384 + offA);
                int offB = sw_off(wn + f * 16 + lr, kbase);
                bh[f] = *(const bf16x8*)(lds + 32768 + offB);
                bl[f] = *(const bf16x8*)(lds + 49152 + offB);
            }
            #pragma unroll
            for (int fm = 0; fm < 4; fm++)
                #pragma unroll
                for (int fn = 0; fn < 4; fn++)
                    acc[fm][fn] = __builtin_amdgcn_mfma_f32_16x16x32_bf16(
                        ah[fm], bh[fn], acc[fm][fn], 0, 0, 0);
            #pragma unroll
            for (int fm = 0; fm < 4; fm++)
                #pragma unroll
                for (int fn = 0; fn < 4; fn++) {
                    acc[fm][fn] = __builtin_amdgcn_mfma_f32_16x16x32_bf16(
                        al[fm], bh[fn], acc[fm][fn], 0, 0, 0);
                    acc[fm][fn] = __builtin_amdgcn_mfma_f32_16x16x32_bf16(
                        ah[fm], bl[fn], acc[fm][fn], 0, 0, 0);
                }
        }
    }

    #pragma unroll
    for (int fn = 0; fn < 4; fn++) {
        int col = bn + wn + fn * 16 + lr;
        if (col < N) {
            float bb = bias ? bias[col] : 0.f;
            #pragma unroll
            for (int fm = 0; fm < 4; fm++) {
                #pragma unroll
                for (int j = 0; j < 4; j++) {
                    int row = bm + wm + fm * 16 + kg * 4 + j;
                    Z[(size_t)row * ldz + col] = acc[fm][fn][j] + bb;
                }
            }
        }
    }
}

// ---------------------------------------------------------------------------
// Grid barrier: flag-per-block + generation counter, agent-scope atomics.
// 64 blocks, all co-resident (1 block/CU at 128 KB LDS). Block 0's 64
// watcher lanes are one wave -> lockstep guarantees all flags seen before
// the gen store. Targets monotonically increase across scans in one launch.
// ---------------------------------------------------------------------------
__device__ __forceinline__ void grid_barrier(unsigned* flags, unsigned* gen,
                                             unsigned target)
{
    __syncthreads();
    if (threadIdx.x == 0) {
        __builtin_amdgcn_fence(__ATOMIC_RELEASE, "agent");
        __hip_atomic_store(&flags[blockIdx.x], target, __ATOMIC_RELAXED,
                           __HIP_MEMORY_SCOPE_AGENT);
    }
    if (blockIdx.x == 0 && threadIdx.x < NB) {
        while (__hip_atomic_load(&flags[threadIdx.x], __ATOMIC_RELAXED,
                                 __HIP_MEMORY_SCOPE_AGENT) < target)
            __builtin_amdgcn_s_sleep(1);
        if (threadIdx.x == 0)
            __hip_atomic_store(gen, target, __ATOMIC_RELEASE,
                               __HIP_MEMORY_SCOPE_AGENT);
    }
    if (threadIdx.x == 0) {
        while (__hip_atomic_load(gen, __ATOMIC_RELAXED,
                                 __HIP_MEMORY_SCOPE_AGENT) < target)
            __builtin_amdgcn_s_sleep(1);
        __builtin_amdgcn_fence(__ATOMIC_ACQUIRE, "agent");
    }
    __syncthreads();
}

// ---------------------------------------------------------------------------
// Persistent LSTM scan: one launch per (layer, stage) scan. 64 blocks x 256.
// Block owns 8 h-columns (jcbase..+7) => 32 rows of Whh (4 gates), staged
// once into LDS as hi/lo bf16 (swizzled). Per step:
//   stage h (hi/lo) -> 48 MFMA per wave (3-pass compensated) -> gates ->
//   write h slice to coherent hbuf -> grid barrier.
// LDS map: A_hi 0..32K, A_lo 32K..64K, B_hi 64K..96K, B_lo 96K..128K.
// a_x (1 KB gate-exchange) aliases A_hi row 0 (restaged every step).
// ---------------------------------------------------------------------------
__global__ __launch_bounds__(256) void lstm_scan_kernel(
    const float* __restrict__ Zx,     // [T, 32, 2048] or nullptr
    const float* __restrict__ bias,   // [2048]
    const float* __restrict__ Whh,    // [2048, 512]
    float* __restrict__ h_state,      // [32, 512] in/out
    float* __restrict__ c_state,      // [32, 512] in/out
    float* __restrict__ out_h,        // [T, 32, 512] or nullptr
    unsigned* hbuf,                   // [2][32][512] packed (hi|lo) bf16
    unsigned* flags, unsigned* gen,
    int T, unsigned base)
{
    __shared__ __align__(16) char lds[131072];
    float* a_x = (float*)lds;         // [32][8] — aliases A_hi row 0

    const int tid  = threadIdx.x;
    const int bid  = blockIdx.x;
    const int wave = tid >> 6;
    const int lane = tid & 63;
    const int mh   = wave >> 1;       // m half (rows b 0-15 / 16-31)
    const int nh   = wave & 1;        // n half (cols i,g / f,o)
    const int lr   = lane & 15;
    const int kg   = lane >> 4;
    const int jcbase = bid * 8;

    // ---- stage B (weights) hi/lo, once ----
    {
        int n  = tid >> 3;                  // 0..31 LDS row
        int k0 = (tid & 7) * 64;
        int gate = (n < 8) ? 0 : (n < 16) ? 2 : (n < 24) ? 1 : 3;  // i,g,f,o
        int jc = n & 7;
        const float* wrow = Whh + ((size_t)gate * 512 + jcbase + jc) * 512;
        for (int j = 0; j < 64; j += 4) {
            float4 v = *(const float4*)&wrow[k0 + j];
            bf16x4 h4, l4; split4(v, h4, l4);
            int off = sw512(n, k0 + j);
            *(bf16x4*)(lds + 65536 + off) = h4;
            *(bf16x4*)(lds + 98304 + off) = l4;
        }
    }

    // lane's output-column mapping (fixed for whole scan)
    const int n_col = nh * 16 + lr;
    const int gate  = (n_col < 8) ? 0 : (n_col < 16) ? 2 : (n_col < 24) ? 1 : 3;
    const int jc    = n_col & 7;
    const int col2048 = gate * 512 + jcbase + jc;
    const float bb = bias[col2048];

    // c state lives in nh==1, lr<8 lanes (4 batches each)
    float cc[4] = {0.f, 0.f, 0.f, 0.f};
    if (nh == 1 && lr < 8) {
        #pragma unroll
        for (int j = 0; j < 4; j++)
            cc[j] = c_state[(mh * 16 + kg * 4 + j) * 512 + jcbase + lr];
    }

    int cur = 0;
    float hnew[4] = {0.f, 0.f, 0.f, 0.f};

    for (int t = 0; t < T; ++t) {
        // ---- stage A (current h) as hi/lo bf16 into LDS ----
        {
            int b  = tid >> 3;
            int k0 = (tid & 7) * 64;
            if (t == 0) {
                const float* hrow = h_state + b * 512;
                for (int j = 0; j < 64; j += 4) {
                    float4 v = *(const float4*)&hrow[k0 + j];
                    bf16x4 h4, l4; split4(v, h4, l4);
                    int off = sw512(b, k0 + j);
                    *(bf16x4*)(lds + off)         = h4;
                    *(bf16x4*)(lds + 32768 + off) = l4;
                }
            } else {
                unsigned* src = hbuf + (cur ^ 1) * 16384 + b * 512 + k0;
                for (int j = 0; j < 64; j += 4) {
                    unsigned u0 = __hip_atomic_load(src + j + 0, __ATOMIC_RELAXED, __HIP_MEMORY_SCOPE_AGENT);
                    unsigned u1 = __hip_atomic_load(src + j + 1, __ATOMIC_RELAXED, __HIP_MEMORY_SCOPE_AGENT);
                    unsigned u2 = __hip_atomic_load(src + j + 2, __ATOMIC_RELAXED, __HIP_MEMORY_SCOPE_AGENT);
                    unsigned u3 = __hip_atomic_load(src + j + 3, __ATOMIC_RELAXED, __HIP_MEMORY_SCOPE_AGENT);
                    union { unsigned short s[4]; bf16x4 v; } H, L;
                    H.s[0] = u0 & 0xffff; L.s[0] = u0 >> 16;
                    H.s[1] = u1 & 0xffff; L.s[1] = u1 >> 16;
                    H.s[2] = u2 & 0xffff; L.s[2] = u2 >> 16;
                    H.s[3] = u3 & 0xffff; L.s[3] = u3 >> 16;
                    int off = sw512(b, k0 + j);
                    *(bf16x4*)(lds + off)         = H.v;
                    *(bf16x4*)(lds + 32768 + off) = L.v;
                }
            }
        }
        __syncthreads();

        // ---- MFMA: z_quadrant = h . W^T (3-pass hi/lo) ----
        f32x4 acc = {0.f, 0.f, 0.f, 0.f};
        const int rowA = mh * 16 + lr;
        const int rowB = nh * 16 + lr;
        #pragma unroll
        for (int ks = 0; ks < 16; ++ks) {
            int k = ks * 32 + kg * 8;
            int offA = sw512(rowA, k);
            int offB = sw512(rowB, k);
            bf16x8 ah = *(const bf16x8*)(lds + offA);
            bf16x8 al = *(const bf16x8*)(lds + 32768 + offA);
            bf16x8 bh = *(const bf16x8*)(lds + 65536 + offB);
            bf16x8 bl = *(const bf16x8*)(lds + 98304 + offB);
            acc = __builtin_amdgcn_mfma_f32_16x16x32_bf16(ah, bh, acc, 0, 0, 0);
            acc = __builtin_amdgcn_mfma_f32_16x16x32_bf16(al, bh, acc, 0, 0, 0);
            acc = __builtin_amdgcn_mfma_f32_16x16x32_bf16(ah, bl, acc, 0, 0, 0);
        }
        __syncthreads();   // all frag reads done (a_x aliases A_hi row 0)

        // ---- finalize z, gate math ----
        float z[4];
        #pragma unroll
        for (int j = 0; j < 4; j++) {
            int b = mh * 16 + kg * 4 + j;
            float zx = Zx ? Zx[(size_t)t * (BSZ * G4) + b * G4 + col2048] : 0.f;
            z[j] = acc[j] + bb + zx;
        }

        if (nh == 0) {
            // lr<8: z=i ; lr>=8: z=g. a = sig(i)*tanh(g)
            float zo[4];
            #pragma unroll
            for (int j = 0; j < 4; j++) zo[j] = __shfl_xor(z[j], 8);
            if (lr < 8) {
                #pragma unroll
                for (int j = 0; j < 4; j++)
                    a_x[(mh * 16 + kg * 4 + j) * 8 + lr] =
                        fast_sigmoid(z[j]) * fast_tanh(zo[j]);
            }
        }
        __syncthreads();

        if (nh == 1) {
            // lr<8: z=f ; lr>=8: z=o
            float cnew[4] = {0.f, 0.f, 0.f, 0.f};
            if (lr < 8) {
                #pragma unroll
                for (int j = 0; j < 4; j++) {
                    float av = a_x[(mh * 16 + kg * 4 + j) * 8 + lr];
                    cnew[j] = fast_sigmoid(z[j]) * cc[j] + av;
                    cc[j] = cnew[j];
                }
            }
            float cfrom[4];
            #pragma unroll
            for (int j = 0; j < 4; j++) cfrom[j] = __shfl_xor(cnew[j], 8);
            if (lr >= 8) {
                #pragma unroll
                for (int j = 0; j < 4; j++) {
                    hnew[j] = fast_sigmoid(z[j]) * fast_tanh(cfrom[j]);
                    int b = mh * 16 + kg * 4 + j;
                    int hcol = jcbase + (lr - 8);
                    if (out_h) out_h[(size_t)t * (BSZ * NHID) + b * 512 + hcol] = hnew[j];
                    __hip_atomic_store(&hbuf[cur * 16384 + b * 512 + hcol],
                                       pack_hilo(hnew[j]), __ATOMIC_RELAXED,
                                       __HIP_MEMORY_SCOPE_AGENT);
                }
            }
        }

        grid_barrier(flags, gen, base + (unsigned)t + 1u);
        cur ^= 1;
    }

    // ---- write back final states ----
    if (nh == 1) {
        if (lr < 8) {
            #pragma unroll
            for (int j = 0; j < 4; j++)
                c_state[(mh * 16 + kg * 4 + j) * 512 + jcbase + lr] = cc[j];
        } else {
            #pragma unroll
            for (int j = 0; j < 4; j++)
                h_state[(mh * 16 + kg * 4 + j) * 512 + jcbase + lr - 8] = hnew[j];
        }
    }
}

// ---------------------------------------------------------------------------
// bias2[j] = l2_b0[j] + sum_h (W_emb[h*NTOK + 0] + b_emb[h]) * Wih0[j*1024 + h]
// ---------------------------------------------------------------------------
__global__ __launch_bounds__(256) void bias2_kernel(
    const float* __restrict__ W_emb,
    const float* __restrict__ b_emb,
    const float* __restrict__ Wih0,
    const float* __restrict__ b0,
    float* __restrict__ bias2)
{
    __shared__ float bos[NHID];
    const int tid = threadIdx.x;
    for (int i = tid; i < NHID; i += 256)
        bos[i] = W_emb[(size_t)i * NTOK] + b_emb[i];
    __syncthreads();
    int j = blockIdx.x * 256 + tid;
    float acc = b0[j];
    for (int k = 0; k < NHID; k++)
        acc += bos[k] * Wih0[(size_t)j * 1024 + k];
    bias2[j] = acc;
}

// ---------------------------------------------------------------------------
// In-place log_softmax over rows of 50257 (online max+sum).
// ---------------------------------------------------------------------------
__global__ __launch_bounds__(256) void logsoftmax_kernel(float* __restrict__ logits)
{
    const size_t row = blockIdx.x;
    float* p = logits + row * (size_t)NTOK;
    const int tid = threadIdx.x;

    float m = -1e30f, s = 0.f;
    for (int i = tid; i < NTOK; i += 256) {
        float x = p[i];
        float mn = fmaxf(m, x);
        s = s * __expf(m - mn) + __expf(x - mn);
        m = mn;
    }
    #pragma unroll
    for (int off = 32; off > 0; off >>= 1) {
        float mo = __shfl_down(m, off);
        float so = __shfl_down(s, off);
        float mn = fmaxf(m, mo);
        s = s * __expf(m - mn) + so * __expf(mo - mn);
        m = mn;
    }
    __shared__ float sm[4], ss[4];
    if ((tid & 63) == 0) { sm[tid >> 6] = m; ss[tid >> 6] = s; }
    __syncthreads();
    float M4 = fmaxf(fmaxf(sm[0], sm[1]), fmaxf(sm[2], sm[3]));
    float S  = ss[0] * __expf(sm[0] - M4) + ss[1] * __expf(sm[1] - M4)
             + ss[2] * __expf(sm[2] - M4) + ss[3] * __expf(sm[3] - M4);
    float lse = M4 + logf(S);
    for (int i = tid; i < NTOK; i += 256) p[i] = p[i] - lse;
}

// ---------------------------------------------------------------------------
extern "C" void kernel_launch(void* const* d_in, const int* in_sizes, int n_in,
                              void* d_out, int out_size, void* d_ws, size_t ws_size,
                              hipStream_t stream)
{
    const float* inp     = (const float*)d_in[0];
    const float* hid1_h  = (const float*)d_in[1];
    const float* hid1_c  = (const float*)d_in[2];
    const float* hid2_h  = (const float*)d_in[3];
    const float* hid2_c  = (const float*)d_in[4];
    const float* l1_Wih0 = (const float*)d_in[5];
    const float* l1_Whh0 = (const float*)d_in[6];
    const float* l1_b0   = (const float*)d_in[7];
    const float* l1_Wih1 = (const float*)d_in[8];
    const float* l1_Whh1 = (const float*)d_in[9];
    const float* l1_b1   = (const float*)d_in[10];
    const float* l2_Wih0 = (const float*)d_in[11];
    const float* l2_Whh0 = (const float*)d_in[12];
    const float* l2_b0   = (const float*)d_in[13];
    const float* l2_Wih1 = (const float*)d_in[14];
    const float* l2_Whh1 = (const float*)d_in[15];
    const float* l2_b1   = (const float*)d_in[16];
    const float* W_out   = (const float*)d_in[17];
    const float* b_out   = (const float*)d_in[18];
    const float* W_emb   = (const float*)d_in[19];
    const float* b_emb   = (const float*)d_in[20];

    float* out = (float*)d_out;   // [40,32,50257]
    float* ws  = (float*)d_ws;

    // workspace layout (floats) — stays within round-2's proven footprint
    float* Zx    = ws;                       // [2560, 2048]
    float* enc0  = ws + 5242880;             // [2560, 512] (reused as dec0)
    float* enc1  = ws + 6553600;             // [2560, 512] (reused as dec1)
    float* enc2  = ws + 7864320;             // [2560, 512] (dec2_0 in rows 0..1279,
                                             //  dec3 overlaps rows 1280..2559)
    float* dec3  = enc2 + 655360;            // [1280, 512] in enc2's free tail
    unsigned* hbuf  = (unsigned*)(ws + 9175040);  // [2][32][512] packed
    unsigned* flags = (unsigned*)(ws + 9207808);  // 64 flags + gen
    unsigned* gen   = flags + 64;
    float* H1    = ws + 9830400;             // [2,32,512]
    float* C1    = H1 + 32768;
    float* H2    = C1 + 32768;
    float* C2    = H2 + 32768;
    float* bias2 = C2 + 32768;               // [2048]

    (void)hipMemsetAsync(flags, 0, 272, stream);   // flags + gen = 0
    (void)hipMemcpyAsync(H1, hid1_h, 131072, hipMemcpyDeviceToDevice, stream);
    (void)hipMemcpyAsync(C1, hid1_c, 131072, hipMemcpyDeviceToDevice, stream);
    (void)hipMemcpyAsync(H2, hid2_h, 131072, hipMemcpyDeviceToDevice, stream);
    (void)hipMemcpyAsync(C2, hid2_c, 131072, hipMemcpyDeviceToDevice, stream);

    auto gemm = [&](const float* X, int lda, const float* W, int ldw,
                    const float* bias, float* Z, int ldz, int M, int N, int K) {
        dim3 grid((N + 127) / 128, M / 128);
        gemm_hilo<<<grid, dim3(256), 0, stream>>>(X, lda, W, ldw, bias, Z, ldz, N, K);
    };
    auto scan = [&](int T, unsigned base, const float* Zx_, const float* bias_,
                    const float* Whh_, float* h_, float* c_, float* outp) {
        lstm_scan_kernel<<<NB, 256, 0, stream>>>(
            Zx_, bias_, Whh_, h_, c_, outp, hbuf, flags, gen, T, base);
    };

    // ---- encoder lstm1 ----
    gemm(inp, NINP, l1_Wih0, NINP, nullptr, Zx, G4, T_ENC * BSZ, G4, NINP);
    scan(T_ENC, 0, Zx, l1_b0, l1_Whh0, H1, C1, enc0);
    gemm(enc0, NHID, l1_Wih1, NHID, nullptr, Zx, G4, T_ENC * BSZ, G4, NHID);
    scan(T_ENC, 80, Zx, l1_b1, l1_Whh1, H1 + 16384, C1 + 16384, enc1);

    // ---- encoder lstm2 (input = [zeros | enc1]) ----
    gemm(enc1, NHID, l2_Wih0 + 512, 2 * NHID, nullptr, Zx, G4, T_ENC * BSZ, G4, NHID);
    scan(T_ENC, 160, Zx, l2_b0, l2_Whh0, H2, C2, enc2);
    gemm(enc2, NHID, l2_Wih1, NHID, nullptr, Zx, G4, T_ENC * BSZ, G4, NHID);
    scan(T_ENC, 240, Zx, l2_b1, l2_Whh1, H2 + 16384, C2 + 16384, nullptr);

    // ---- decoder lstm1 (input = zeros -> bias only for layer 0) ----
    scan(T_DEC, 320, nullptr, l1_b0, l1_Whh0, H1, C1, enc0 /* dec0 */);
    gemm(enc0, NHID, l1_Wih1, NHID, nullptr, Zx, G4, T_DEC * BSZ, G4, NHID);
    scan(T_DEC, 360, Zx, l1_b1, l1_Whh1, H1 + 16384, C1 + 16384, enc1 /* dec1 */);

    // ---- decoder lstm2 (input = [const BOS emb | dec1]) ----
    bias2_kernel<<<8, 256, 0, stream>>>(W_emb, b_emb, l2_Wih0, l2_b0, bias2);
    gemm(enc1, NHID, l2_Wih0 + 512, 2 * NHID, nullptr, Zx, G4, T_DEC * BSZ, G4, NHID);
    scan(T_DEC, 400, Zx, bias2, l2_Whh0, H2, C2, enc2 /* dec2_0 */);
    gemm(enc2, NHID, l2_Wih1, NHID, nullptr, Zx, G4, T_DEC * BSZ, G4, NHID);
    scan(T_DEC, 440, Zx, l2_b1, l2_Whh1, H2 + 16384, C2 + 16384, dec3);

    // ---- vocab projection + log_softmax ----
    gemm(dec3, NHID, W_out, NHID, b_out, out, NTOK, T_DEC * BSZ, NTOK, NHID);
    logsoftmax_kernel<<<1280, dim3(256), 0, stream>>>(out);
}

// Round 5
// 2040.528 us; speedup vs baseline: 15.5311x; 3.6129x over previous
//
#include <hip/hip_runtime.h>
#include <hip/hip_bf16.h>
#include <cstddef>

// Problem constants (fixed by the harness shapes)
#define NINP 4096
#define NHID 512
#define G4   2048   // 4*NHID
#define NTOK 50257
#define BSZ  32
#define T_ENC 80
#define T_DEC 40

typedef __attribute__((ext_vector_type(4))) float  f32x4;
typedef __attribute__((ext_vector_type(4))) __bf16 bf16x4;
typedef __attribute__((ext_vector_type(8))) __bf16 bf16x8;

// ---------------------------------------------------------------------------
// XOR-swizzled byte offsets (row-major bf16 tiles, 16B-slot XOR row&7)
// ---------------------------------------------------------------------------
__device__ __forceinline__ int sw_off(int r, int k) {   // [rows][64] bf16
    return r * 128 + ((((k >> 3) ^ (r & 7)) << 4) | ((k & 7) << 1));
}
__device__ __forceinline__ int sw512(int r, int k) {    // [rows][512] bf16
    return r * 1024 + ((((k >> 3) ^ (r & 7)) << 4) | ((k & 7) << 1));
}

__device__ __forceinline__ void split4(const float4& v, bf16x4& h, bf16x4& l) {
    float a0 = v.x, a1 = v.y, a2 = v.z, a3 = v.w;
    __bf16 h0 = (__bf16)a0, h1 = (__bf16)a1, h2 = (__bf16)a2, h3 = (__bf16)a3;
    h[0] = h0; h[1] = h1; h[2] = h2; h[3] = h3;
    l[0] = (__bf16)(a0 - (float)h0);
    l[1] = (__bf16)(a1 - (float)h1);
    l[2] = (__bf16)(a2 - (float)h2);
    l[3] = (__bf16)(a3 - (float)h3);
}

__device__ __forceinline__ bf16x4 hi4(const float4& v) {
    bf16x4 h; h[0] = (__bf16)v.x; h[1] = (__bf16)v.y;
    h[2] = (__bf16)v.z; h[3] = (__bf16)v.w; return h;
}

__device__ __forceinline__ void split8(const float4& a, const float4& b,
                                       bf16x8& h, bf16x8& l) {
    float x[8] = {a.x, a.y, a.z, a.w, b.x, b.y, b.z, b.w};
    #pragma unroll
    for (int i = 0; i < 8; i++) {
        __bf16 hb = (__bf16)x[i];
        h[i] = hb; l[i] = (__bf16)(x[i] - (float)hb);
    }
}

__device__ __forceinline__ bf16x8 to_bf16x8(const float4& a, const float4& b) {
    bf16x8 r;
    r[0]=(__bf16)a.x; r[1]=(__bf16)a.y; r[2]=(__bf16)a.z; r[3]=(__bf16)a.w;
    r[4]=(__bf16)b.x; r[5]=(__bf16)b.y; r[6]=(__bf16)b.z; r[7]=(__bf16)b.w;
    return r;
}

__device__ __forceinline__ void unpack8(const uint4& a, const uint4& b,
                                        bf16x8& h, bf16x8& l) {
    unsigned u[8] = {a.x, a.y, a.z, a.w, b.x, b.y, b.z, b.w};
    union { unsigned short s; __bf16 v; } t;
    #pragma unroll
    for (int i = 0; i < 8; i++) {
        t.s = (unsigned short)(u[i] & 0xffff); h[i] = t.v;
        t.s = (unsigned short)(u[i] >> 16);    l[i] = t.v;
    }
}
__device__ __forceinline__ bf16x8 unpack_hi8(const uint4& a, const uint4& b) {
    unsigned u[8] = {a.x, a.y, a.z, a.w, b.x, b.y, b.z, b.w};
    union { unsigned short s; __bf16 v; } t;
    bf16x8 h;
    #pragma unroll
    for (int i = 0; i < 8; i++) { t.s = (unsigned short)(u[i] & 0xffff); h[i] = t.v; }
    return h;
}

__device__ __forceinline__ unsigned pack_hilo(float x) {
    __bf16 hb = (__bf16)x;
    float hf = (float)hb;
    __bf16 lb = (__bf16)(x - hf);
    union { __bf16 b; unsigned short s; } ch, cl;
    ch.b = hb; cl.b = lb;
    return (unsigned)ch.s | ((unsigned)cl.s << 16);
}

__device__ __forceinline__ float fast_sigmoid(float x) {
    return 1.f / (1.f + __expf(-x));
}
__device__ __forceinline__ float fast_tanh(float x) {
    return 1.f - 2.f / (__expf(2.f * x) + 1.f);
}

// ---------------------------------------------------------------------------
// Compensated bf16 MFMA GEMM (2-pass: Ah*Bh + Al*Bh; B quantized to bf16):
// Z[m][n] = bias[n] + sum_k A[m][k]*B[n][k]. 128x128 tile, BK=64, 4 waves.
// LDS: A_hi 0..16K, A_lo 16K..32K, B_hi 32K..48K.
// ---------------------------------------------------------------------------
__global__ __launch_bounds__(256) void gemm_hilo(
    const float* __restrict__ A, int lda,
    const float* __restrict__ B, int ldb,
    const float* __restrict__ bias,
    float* __restrict__ Z, int ldz,
    int N, int K)
{
    __shared__ __align__(16) char lds[49152];
    const int tid  = threadIdx.x;
    const int bm   = blockIdx.y * 128;
    const int bn   = blockIdx.x * 128;
    const int wave = tid >> 6;
    const int lane = tid & 63;
    const int wm   = (wave >> 1) * 64;
    const int wn   = (wave & 1) * 64;
    const int lr   = lane & 15;
    const int kg   = lane >> 4;

    const int rr = tid >> 4;
    const int kk = (tid & 15) * 4;

    f32x4 acc[4][4] = {};

    for (int k0 = 0; k0 < K; k0 += 64) {
        float4 av[8], bv[8];
        #pragma unroll
        for (int i = 0; i < 8; i++) {
            int r = i * 16 + rr;
            av[i] = *(const float4*)&A[(size_t)(bm + r) * lda + k0 + kk];
            int rb = bn + r;
            if (rb < N)
                bv[i] = *(const float4*)&B[(size_t)rb * ldb + k0 + kk];
            else
                bv[i] = make_float4(0.f, 0.f, 0.f, 0.f);
        }
        __syncthreads();
        #pragma unroll
        for (int i = 0; i < 8; i++) {
            int r = i * 16 + rr;
            int off = sw_off(r, kk);
            bf16x4 h, l;
            split4(av[i], h, l);
            *(bf16x4*)(lds + off)         = h;
            *(bf16x4*)(lds + 16384 + off) = l;
            *(bf16x4*)(lds + 32768 + off) = hi4(bv[i]);
        }
        __syncthreads();
        #pragma unroll
        for (int ks = 0; ks < 2; ks++) {
            bf16x8 ah[4], al[4], bh[4];
            const int kbase = ks * 32 + kg * 8;
            #pragma unroll
            for (int f = 0; f < 4; f++) {
                int offA = sw_off(wm + f * 16 + lr, kbase);
                ah[f] = *(const bf16x8*)(lds + offA);
                al[f] = *(const bf16x8*)(lds + 16384 + offA);
                int offB = sw_off(wn + f * 16 + lr, kbase);
                bh[f] = *(const bf16x8*)(lds + 32768 + offB);
            }
            #pragma unroll
            for (int fm = 0; fm < 4; fm++)
                #pragma unroll
                for (int fn = 0; fn < 4; fn++) {
                    acc[fm][fn] = __builtin_amdgcn_mfma_f32_16x16x32_bf16(
                        ah[fm], bh[fn], acc[fm][fn], 0, 0, 0);
                    acc[fm][fn] = __builtin_amdgcn_mfma_f32_16x16x32_bf16(
                        al[fm], bh[fn], acc[fm][fn], 0, 0, 0);
                }
        }
    }

    #pragma unroll
    for (int fn = 0; fn < 4; fn++) {
        int col = bn + wn + fn * 16 + lr;
        if (col < N) {
            float bb = bias ? bias[col] : 0.f;
            #pragma unroll
            for (int fm = 0; fm < 4; fm++) {
                #pragma unroll
                for (int j = 0; j < 4; j++) {
                    int row = bm + wm + fm * 16 + kg * 4 + j;
                    Z[(size_t)row * ldz + col] = acc[fm][fn][j] + bb;
                }
            }
        }
    }
}

// ---------------------------------------------------------------------------
// Grid barrier (256 blocks, 1/CU co-resident). flags[256] + gen.
// ---------------------------------------------------------------------------
__device__ __forceinline__ void grid_barrier(unsigned* flags, unsigned* gen,
                                             unsigned target)
{
    __syncthreads();
    if (threadIdx.x == 0) {
        __builtin_amdgcn_fence(__ATOMIC_RELEASE, "agent");
        __hip_atomic_store(&flags[blockIdx.x], target, __ATOMIC_RELAXED,
                           __HIP_MEMORY_SCOPE_AGENT);
    }
    if (blockIdx.x == 0) {
        while (__hip_atomic_load(&flags[threadIdx.x], __ATOMIC_RELAXED,
                                 __HIP_MEMORY_SCOPE_AGENT) < target)
            __builtin_amdgcn_s_sleep(1);
        __syncthreads();
        if (threadIdx.x == 0)
            __hip_atomic_store(gen, target, __ATOMIC_RELAXED,
                               __HIP_MEMORY_SCOPE_AGENT);
    }
    if (threadIdx.x == 0) {
        while (__hip_atomic_load(gen, __ATOMIC_RELAXED,
                                 __HIP_MEMORY_SCOPE_AGENT) < target)
            __builtin_amdgcn_s_sleep(1);
        __builtin_amdgcn_fence(__ATOMIC_ACQUIRE, "agent");
    }
    __syncthreads();
}

// ---------------------------------------------------------------------------
// Fused 4-layer pipelined LSTM scan, encoder+decoder in ONE launch.
// 256 blocks: layer L = blockIdx>>6 (64 col-blocks each). Global step tt:
// layer L processes myt = tt-L (0..119; <80 = encoder, >=80 = decoder).
// z = x@Wih^T (hi*hi) + h@Whh^T (2-pass hi/lo * hi) + bias [+ Zx for L0 enc].
// h broadcast between layers/blocks via LLC-coherent hbuf (packed hi|lo u32).
// LDS: A_hi 0..32K, A_lo 32K..64K (a_x aliases), Whh_hi 64K..96K,
//      Wih_hi 96K..128K.
// ---------------------------------------------------------------------------
__global__ __launch_bounds__(256, 1) void fused_scan(
    const float* __restrict__ Zx,
    const float* __restrict__ Whh_0, const float* __restrict__ bias_0,
    const float* __restrict__ Wih_1, const float* __restrict__ Whh_1,
    const float* __restrict__ bias_1,
    const float* __restrict__ Wih_2, const float* __restrict__ Whh_2,
    const float* __restrict__ bias_2e, const float* __restrict__ bias_2d,
    const float* __restrict__ Wih_3, const float* __restrict__ Whh_3,
    const float* __restrict__ bias_3,
    const float* __restrict__ hid1_h, const float* __restrict__ hid1_c,
    const float* __restrict__ hid2_h, const float* __restrict__ hid2_c,
    float* __restrict__ dec3,
    unsigned* hbuf, unsigned* flags, unsigned* gen)
{
    __shared__ __align__(16) char lds[131072];
    float* a_x = (float*)(lds + 32768);   // aliases A_lo (restaged each step)

    const int tid  = threadIdx.x;
    const int L    = blockIdx.x >> 6;
    const int bidc = blockIdx.x & 63;
    const int wave = tid >> 6;
    const int lane = tid & 63;
    const int mh   = wave >> 1;
    const int nh   = wave & 1;
    const int lr   = lane & 15;
    const int kg   = lane >> 4;
    const int jcbase = bidc * 8;
    const int bq = tid >> 3;     // staging row 0..31
    const int aq = tid & 7;      // staging k-lane

    const float* Whh = (L==0)?Whh_0:(L==1)?Whh_1:(L==2)?Whh_2:Whh_3;
    const float* Wih = (L==1)?Wih_1:(L==2)?Wih_2:(L==3)?Wih_3:nullptr;
    const int ld_ih  = (L==2)?1024:512;
    const float* be  = (L==0)?bias_0:(L==1)?bias_1:(L==2)?bias_2e:bias_3;
    const float* bd  = (L==2)?bias_2d:be;
    const float* h0  = ((L<2)?hid1_h:hid2_h) + (L&1)*16384;
    const float* c0  = ((L<2)?hid1_c:hid2_c) + (L&1)*16384;
    unsigned* myb       = hbuf + L*32768;
    const unsigned* xsb = hbuf + (L>0 ? (L-1)*32768 : 0);

    // ---- stage weights hi-only, once (conflict-free mapping) ----
    {
        int gate = (bq<8)?0:(bq<16)?2:(bq<24)?1:3;   // rows: i,g,f,o
        int row  = gate*512 + jcbase + (bq&7);
        const float* wr = Whh + (size_t)row * 512;
        #pragma unroll
        for (int jj = 0; jj < 8; jj++) {
            int k = aq*8 + jj*64;
            *(bf16x8*)(lds + 65536 + sw512(bq, k)) =
                to_bf16x8(*(const float4*)(wr+k), *(const float4*)(wr+k+4));
        }
        if (Wih) {
            const float* wr2 = Wih + (size_t)row * ld_ih;
            #pragma unroll
            for (int jj = 0; jj < 8; jj++) {
                int k = aq*8 + jj*64;
                *(bf16x8*)(lds + 98304 + sw512(bq, k)) =
                    to_bf16x8(*(const float4*)(wr2+k), *(const float4*)(wr2+k+4));
            }
        }
    }

    // lane's output-column mapping
    const int n_col = nh*16 + lr;
    const int gate  = (n_col<8)?0:(n_col<16)?2:(n_col<24)?1:3;
    const int col2048 = gate*512 + jcbase + (n_col & 7);
    const float bbe = be[col2048];
    const float bbd = bd[col2048];

    // c state: nh==1, lr<8 lanes, 4 batches each
    float cc[4] = {0.f, 0.f, 0.f, 0.f};
    if (nh == 1 && lr < 8) {
        #pragma unroll
        for (int j = 0; j < 4; j++)
            cc[j] = c0[(mh*16 + kg*4 + j)*512 + jcbase + lr];
    }
    __syncthreads();

    const int rowA = mh*16 + lr;
    const int rowB = nh*16 + lr;

    for (int tt = 0; tt < 123; ++tt) {
        const int myt = tt - L;
        if (myt >= 0 && myt < 120) {
            // ---- hoist x loads (L>=1) ----
            uint4 xr[8][2];
            if (L > 0) {
                const unsigned* xs = xsb + (size_t)(myt & 1)*16384 + bq*512;
                #pragma unroll
                for (int jj = 0; jj < 8; jj++) {
                    int k = aq*8 + jj*64;
                    xr[jj][0] = *(const uint4*)(xs + k);
                    xr[jj][1] = *(const uint4*)(xs + k + 4);
                }
            }
            // ---- stage h (hi/lo) ----
            if (myt == 0) {
                const float* hr = h0 + bq*512;
                #pragma unroll
                for (int jj = 0; jj < 8; jj++) {
                    int k = aq*8 + jj*64;
                    bf16x8 H, Lo;
                    split8(*(const float4*)(hr+k), *(const float4*)(hr+k+4), H, Lo);
                    int off = sw512(bq, k);
                    *(bf16x8*)(lds + off)         = H;
                    *(bf16x8*)(lds + 32768 + off) = Lo;
                }
            } else {
                const unsigned* hs = myb + (size_t)((myt-1) & 1)*16384 + bq*512;
                #pragma unroll
                for (int jj = 0; jj < 8; jj++) {
                    int k = aq*8 + jj*64;
                    bf16x8 H, Lo;
                    unpack8(*(const uint4*)(hs+k), *(const uint4*)(hs+k+4), H, Lo);
                    int off = sw512(bq, k);
                    *(bf16x8*)(lds + off)         = H;
                    *(bf16x8*)(lds + 32768 + off) = Lo;
                }
            }
            __syncthreads();

            // ---- phase 1: h @ Whh^T (2-pass, split accumulators) ----
            f32x4 accA = {0.f,0.f,0.f,0.f}, accB = {0.f,0.f,0.f,0.f};
            #pragma unroll
            for (int ks = 0; ks < 16; ++ks) {
                int k = ks*32 + kg*8;
                int offA = sw512(rowA, k);
                int offB = sw512(rowB, k);
                bf16x8 ah = *(const bf16x8*)(lds + offA);
                bf16x8 al = *(const bf16x8*)(lds + 32768 + offA);
                bf16x8 bh = *(const bf16x8*)(lds + 65536 + offB);
                accA = __builtin_amdgcn_mfma_f32_16x16x32_bf16(ah, bh, accA, 0,0,0);
                accB = __builtin_amdgcn_mfma_f32_16x16x32_bf16(al, bh, accB, 0,0,0);
            }
            __syncthreads();

            // ---- phase 2: x @ Wih^T (hi only) ----
            if (L > 0) {
                #pragma unroll
                for (int jj = 0; jj < 8; jj++) {
                    int k = aq*8 + jj*64;
                    *(bf16x8*)(lds + sw512(bq, k)) = unpack_hi8(xr[jj][0], xr[jj][1]);
                }
                __syncthreads();
                #pragma unroll
                for (int ks = 0; ks < 16; ++ks) {
                    int k = ks*32 + kg*8;
                    bf16x8 ax = *(const bf16x8*)(lds + sw512(rowA, k));
                    bf16x8 bi = *(const bf16x8*)(lds + 98304 + sw512(rowB, k));
                    accA = __builtin_amdgcn_mfma_f32_16x16x32_bf16(ax, bi, accA, 0,0,0);
                }
            }

            // ---- finalize z, gates ----
            const float bbv = (L == 2 && myt >= 80) ? bbd : bbe;
            float z[4];
            #pragma unroll
            for (int j = 0; j < 4; j++) {
                int b = mh*16 + kg*4 + j;
                float zx = (L == 0 && myt < 80)
                    ? Zx[(size_t)myt*(BSZ*G4) + b*G4 + col2048] : 0.f;
                z[j] = accA[j] + accB[j] + bbv + zx;
            }

            if (nh == 0) {
                // lr<8: z=i ; lr>=8: z=g -> a = sig(i)*tanh(g)
                float zo[4];
                #pragma unroll
                for (int j = 0; j < 4; j++) zo[j] = __shfl_xor(z[j], 8);
                if (lr < 8) {
                    #pragma unroll
                    for (int j = 0; j < 4; j++)
                        a_x[(mh*16 + kg*4 + j)*8 + lr] =
                            fast_sigmoid(z[j]) * fast_tanh(zo[j]);
                }
            }
            __syncthreads();

            if (nh == 1) {
                // lr<8: z=f ; lr>=8: z=o
                float cnew[4] = {0.f,0.f,0.f,0.f};
                if (lr < 8) {
                    #pragma unroll
                    for (int j = 0; j < 4; j++) {
                        float av = a_x[(mh*16 + kg*4 + j)*8 + lr];
                        cnew[j] = fast_sigmoid(z[j]) * cc[j] + av;
                        cc[j] = cnew[j];
                    }
                }
                float cfrom[4];
                #pragma unroll
                for (int j = 0; j < 4; j++) cfrom[j] = __shfl_xor(cnew[j], 8);
                if (lr >= 8) {
                    #pragma unroll
                    for (int j = 0; j < 4; j++) {
                        float hn = fast_sigmoid(z[j]) * fast_tanh(cfrom[j]);
                        int b = mh*16 + kg*4 + j;
                        int hcol = jcbase + (lr - 8);
                        if (L == 3 && myt >= 80)
                            dec3[(size_t)(myt-80)*(BSZ*NHID) + b*512 + hcol] = hn;
                        __hip_atomic_store(&myb[(size_t)(myt & 1)*16384 + b*512 + hcol],
                                           pack_hilo(hn), __ATOMIC_RELAXED,
                                           __HIP_MEMORY_SCOPE_AGENT);
                    }
                }
            }
        }
        grid_barrier(flags, gen, (unsigned)tt + 1u);
    }
}

// ---------------------------------------------------------------------------
// bias2[j] = l2_b0[j] + sum_h (W_emb[h*NTOK+0] + b_emb[h]) * Wih0[j*1024+h]
// ---------------------------------------------------------------------------
__global__ __launch_bounds__(256) void bias2_kernel(
    const float* __restrict__ W_emb,
    const float* __restrict__ b_emb,
    const float* __restrict__ Wih0,
    const float* __restrict__ b0,
    float* __restrict__ bias2)
{
    __shared__ float bos[NHID];
    const int tid = threadIdx.x;
    for (int i = tid; i < NHID; i += 256)
        bos[i] = W_emb[(size_t)i * NTOK] + b_emb[i];
    __syncthreads();
    int j = blockIdx.x * 256 + tid;
    float acc = b0[j];
    for (int k = 0; k < NHID; k++)
        acc += bos[k] * Wih0[(size_t)j * 1024 + k];
    bias2[j] = acc;
}

// ---------------------------------------------------------------------------
// In-place log_softmax over rows of 50257 (online max+sum).
// ---------------------------------------------------------------------------
__global__ __launch_bounds__(256) void logsoftmax_kernel(float* __restrict__ logits)
{
    const size_t row = blockIdx.x;
    float* p = logits + row * (size_t)NTOK;
    const int tid = threadIdx.x;

    float m = -1e30f, s = 0.f;
    for (int i = tid; i < NTOK; i += 256) {
        float x = p[i];
        float mn = fmaxf(m, x);
        s = s * __expf(m - mn) + __expf(x - mn);
        m = mn;
    }
    #pragma unroll
    for (int off = 32; off > 0; off >>= 1) {
        float mo = __shfl_down(m, off);
        float so = __shfl_down(s, off);
        float mn = fmaxf(m, mo);
        s = s * __expf(m - mn) + so * __expf(mo - mn);
        m = mn;
    }
    __shared__ float sm[4], ss[4];
    if ((tid & 63) == 0) { sm[tid >> 6] = m; ss[tid >> 6] = s; }
    __syncthreads();
    float M4 = fmaxf(fmaxf(sm[0], sm[1]), fmaxf(sm[2], sm[3]));
    float S  = ss[0] * __expf(sm[0] - M4) + ss[1] * __expf(sm[1] - M4)
             + ss[2] * __expf(sm[2] - M4) + ss[3] * __expf(sm[3] - M4);
    float lse = M4 + logf(S);
    for (int i = tid; i < NTOK; i += 256) p[i] = p[i] - lse;
}

// ---------------------------------------------------------------------------
extern "C" void kernel_launch(void* const* d_in, const int* in_sizes, int n_in,
                              void* d_out, int out_size, void* d_ws, size_t ws_size,
                              hipStream_t stream)
{
    const float* inp     = (const float*)d_in[0];
    const float* hid1_h  = (const float*)d_in[1];
    const float* hid1_c  = (const float*)d_in[2];
    const float* hid2_h  = (const float*)d_in[3];
    const float* hid2_c  = (const float*)d_in[4];
    const float* l1_Wih0 = (const float*)d_in[5];
    const float* l1_Whh0 = (const float*)d_in[6];
    const float* l1_b0   = (const float*)d_in[7];
    const float* l1_Wih1 = (const float*)d_in[8];
    const float* l1_Whh1 = (const float*)d_in[9];
    const float* l1_b1   = (const float*)d_in[10];
    const float* l2_Wih0 = (const float*)d_in[11];
    const float* l2_Whh0 = (const float*)d_in[12];
    const float* l2_b0   = (const float*)d_in[13];
    const float* l2_Wih1 = (const float*)d_in[14];
    const float* l2_Whh1 = (const float*)d_in[15];
    const float* l2_b1   = (const float*)d_in[16];
    const float* W_out   = (const float*)d_in[17];
    const float* b_out   = (const float*)d_in[18];
    const float* W_emb   = (const float*)d_in[19];
    const float* b_emb   = (const float*)d_in[20];

    float* out = (float*)d_out;   // [40,32,50257]
    float* ws  = (float*)d_ws;

    // workspace layout (floats)
    float* Zx    = ws;                           // [2560,2048] = 5,242,880
    float* dec3  = ws + 5242880;                 // [1280,512]  =   655,360
    float* bias2 = ws + 5898240;                 // [2048]
    unsigned* hbuf  = (unsigned*)(ws + 5900288); // [4][2][32][512] u32
    unsigned* flags = (unsigned*)(ws + 6031360); // 256 flags + gen
    unsigned* gen   = flags + 256;

    (void)hipMemsetAsync(flags, 0, 1028, stream);

    // input projection for encoder lstm1 layer0 (the only precomputed Zx)
    {
        dim3 grid((G4 + 127) / 128, (T_ENC * BSZ) / 128);
        gemm_hilo<<<grid, dim3(256), 0, stream>>>(
            inp, NINP, l1_Wih0, NINP, nullptr, Zx, G4, G4, NINP);
    }
    bias2_kernel<<<8, 256, 0, stream>>>(W_emb, b_emb, l2_Wih0, l2_b0, bias2);

    // fused pipelined scan: all 4 layers, encoder + decoder, one launch
    fused_scan<<<256, 256, 0, stream>>>(
        Zx,
        l1_Whh0, l1_b0,
        l1_Wih1, l1_Whh1, l1_b1,
        l2_Wih0 + 512, l2_Whh0, l2_b0, bias2,
        l2_Wih1, l2_Whh1, l2_b1,
        hid1_h, hid1_c, hid2_h, hid2_c,
        dec3, hbuf, flags, gen);

    // vocab projection + log_softmax
    {
        dim3 grid((NTOK + 127) / 128, (T_DEC * BSZ) / 128);
        gemm_hilo<<<grid, dim3(256), 0, stream>>>(
            dec3, NHID, W_out, NHID, b_out, out, NTOK, NTOK, NHID);
    }
    logsoftmax_kernel<<<1280, dim3(256), 0, stream>>>(out);
}